// Round 8
// baseline (607.886 us; speedup 1.0000x reference)
//
#include <hip/hip_runtime.h>
#include <hip/hip_bf16.h>
#include <math.h>

#define N_NODES 50000
#define N_EDGES 800000
#define CLAMP_V 5.0f

typedef short short8 __attribute__((ext_vector_type(8)));
typedef float f32x4  __attribute__((ext_vector_type(4)));

static __device__ inline short f2bf(float x) {
    __hip_bfloat16 h = __float2bfloat16(x);   // RNE
    return __builtin_bit_cast(short, h);
}
static __device__ inline float bf2f(short s) {
    unsigned u = ((unsigned)(unsigned short)s) << 16;
    return __builtin_bit_cast(float, u);
}

// ---------------- Kernel 1: Q/K/V node projections (unchanged, proven) ----------------
__global__ __launch_bounds__(256) void qkv_kernel(
    const float* __restrict__ x,
    const float* __restrict__ WQ, const float* __restrict__ bQ,
    const float* __restrict__ WK, const float* __restrict__ bK,
    const float* __restrict__ WV, const float* __restrict__ bV,
    float* __restrict__ Q, float* __restrict__ K, float* __restrict__ V)
{
    const int t = threadIdx.x;
    const int c = t & 63;
    const int nl = t >> 6;
    const int base = blockIdx.x * 16;

    float accQ[4], accK[4], accV[4];
    int nodes[4];
#pragma unroll
    for (int j = 0; j < 4; ++j) {
        nodes[j] = base + j * 4 + nl;
        accQ[j] = bQ[c]; accK[j] = bK[c]; accV[j] = bV[c];
    }
    for (int k = 0; k < 64; ++k) {
        const float wq = WQ[k * 64 + c];
        const float wk = WK[k * 64 + c];
        const float wv = WV[k * 64 + c];
#pragma unroll
        for (int j = 0; j < 4; ++j) {
            const float xv = x[nodes[j] * 64 + k];
            accQ[j] += xv * wq;
            accK[j] += xv * wk;
            accV[j] += xv * wv;
        }
    }
#pragma unroll
    for (int j = 0; j < 4; ++j) {
        const int n = nodes[j];
        Q[n * 64 + c] = accQ[j];
        K[n * 64 + c] = accK[j];
        V[n * 64 + c] = accV[j];
    }
}

// ---------------- Kernel 2: fused E-GEMM + score + denom + numerator ----------------
// R7 skeleton (proven, 263us). This round: bE moved from LDS to 8 per-lane
// registers -> LDS drops 41472 -> 40960 B -> 4 blocks/CU (16 waves, 4/SIMD,
// was 3/SIMD). __launch_bounds__(256,4): VGPR cap 128 (using ~84).
__global__ __launch_bounds__(256, 4) void edge_kernel(
    const float* __restrict__ edge_attr,
    const int* __restrict__ src_idx, const int* __restrict__ dst_idx,
    const float* __restrict__ WE, const float* __restrict__ bE,
    const float* __restrict__ Aw,
    const float* __restrict__ Qn, const float* __restrict__ Kn,
    const float* __restrict__ Vn, const float* __restrict__ VeRow,
    float* __restrict__ wE_out, float* __restrict__ denom,
    float* __restrict__ wV_num)
{
    // [0,16K)=B_hi  [16K,32K)=B_lo  [32K,40K)=E transpose buf (2KB/wave)
    __shared__ __align__(16) char raw[40960];

    short8* Bhi = (short8*)raw;                  // [(ct*2+kh)*64 + lane]
    short8* Blo = (short8*)(raw + 16384);

    const int t = threadIdx.x;
    const int wave = t >> 6;
    const int lane = t & 63;

    // ---- init: bf16 hi/lo B-fragments from global WE
    short* BhiE = (short*)raw;
    short* BloE = (short*)(raw + 16384);
    for (int i = t; i < 8192; i += 256) {
        const int j  = i & 7;
        const int ln = (i >> 3) & 63;
        const int kh = (i >> 9) & 1;
        const int ct = i >> 10;
        const int k   = kh * 32 + ((ln >> 4) << 3) + j;
        const int col = (ct << 4) + (ln & 15);
        const float w = WE[k * 128 + col];
        const short hb = f2bf(w);
        BhiE[i] = hb;
        BloE[i] = f2bf(w - bf2f(hb));
    }
    __syncthreads();

    float* Ebuf_w = (float*)(raw + 32768 + wave * 2048);  // [col*4 + rr]

    const int h    = lane >> 3;
    const int kk   = lane & 7;
    const int g    = lane >> 4;
    const int c4   = lane & 15;
    const int h16k = (h << 4) + kk;

    // loop-invariant weights in registers (global reads, once, L2-hot)
    const float aw = Aw[kk * 8 + h];
    float veR[8];
#pragma unroll
    for (int dd = 0; dd < 8; ++dd) veR[dd] = VeRow[dd * 64 + lane];
    // bias registers: lane's 8 columns (ct<<4)+c4, statically indexed by ct
    float bEr[8];
#pragma unroll
    for (int ct = 0; ct < 8; ++ct) bEr[ct] = bE[(ct << 4) + c4];

    const int G = (int)gridDim.x;

    // ---- pipeline state: current A-raw + indices; next A-raw + indices
    float4 arC[4], arN[4];
    int seC[16], deC[16], seN[16], deN[16];

    // ---- prologue: load A-raw + indices for first iteration
    int it = blockIdx.x;
    {
        const int ebase0 = __builtin_amdgcn_readfirstlane(it * 64 + wave * 16);
#pragma unroll
        for (int p = 0; p < 2; ++p) {
            const float* srcp = edge_attr + (size_t)(ebase0 + c4) * 64 + p * 32 + (g << 3);
            arC[2 * p]     = *(const float4*)srcp;
            arC[2 * p + 1] = *(const float4*)(srcp + 4);
        }
#pragma unroll
        for (int r = 0; r < 16; ++r) {
            seC[r] = src_idx[ebase0 + r];
            deC[r] = dst_idx[ebase0 + r];
        }
    }

    for (; it < 12500; it += G) {
        const int ebaseC = __builtin_amdgcn_readfirstlane(it * 64 + wave * 16);
        const int itN    = it + G;
        const int itNc   = (itN < 12500) ? itN : 0;   // clamped (result unused at tail)
        const int ebaseN = __builtin_amdgcn_readfirstlane(itNc * 64 + wave * 16);

        // ---- convert A(cur) -> bf16 hi/lo (arC landed long ago; no wait)
        short8 ah[2], al[2];
#pragma unroll
        for (int p = 0; p < 2; ++p) {
            const float xv[8] = {arC[2*p].x, arC[2*p].y, arC[2*p].z, arC[2*p].w,
                                 arC[2*p+1].x, arC[2*p+1].y, arC[2*p+1].z, arC[2*p+1].w};
#pragma unroll
            for (int j = 0; j < 8; ++j) {
                const short hb = f2bf(xv[j]);
                ah[p][j] = hb;
                al[p][j] = f2bf(xv[j] - bf2f(hb));
            }
        }

        // ---- next-iteration index scalar loads (lgkm; land during MFMA)
#pragma unroll
        for (int r = 0; r < 16; ++r) {
            seN[r] = src_idx[ebaseN + r];
            deN[r] = dst_idx[ebaseN + r];
        }

        // ---- gathers for CURRENT iteration (consumed in score phase):
        // issue BEFORE arN so score's vmcnt waits don't drain the prefetch
        float vv[16], kv[16], qv[16];
#pragma unroll
        for (int r = 0; r < 16; ++r) vv[r] = Vn[seC[r] * 64 + lane];
#pragma unroll
        for (int r = 0; r < 16; ++r) {
            kv[r] = Kn[seC[r] * 64 + lane];
            qv[r] = Qn[deC[r] * 64 + lane];
        }

        // ---- A(next) raw loads: issued last, consumed at body end
#pragma unroll
        for (int p = 0; p < 2; ++p) {
            const float* srcp = edge_attr + (size_t)(ebaseN + c4) * 64 + p * 32 + (g << 3);
            arN[2 * p]     = *(const float4*)srcp;
            arN[2 * p + 1] = *(const float4*)(srcp + 4);
        }

        // ---- MFMA: acc[ct] = E[16 rows][ct*16..+15]  (3-product bf16 split)
        f32x4 acc[8] = {};
#pragma unroll
        for (int kh = 0; kh < 2; ++kh) {
#pragma unroll
            for (int ct = 0; ct < 8; ++ct) {
                const short8 bh = Bhi[(ct * 2 + kh) * 64 + lane];
                const short8 bl = Blo[(ct * 2 + kh) * 64 + lane];
                acc[ct] = __builtin_amdgcn_mfma_f32_16x16x32_bf16(ah[kh], bh, acc[ct], 0, 0, 0);
                acc[ct] = __builtin_amdgcn_mfma_f32_16x16x32_bf16(al[kh], bh, acc[ct], 0, 0, 0);
                acc[ct] = __builtin_amdgcn_mfma_f32_16x16x32_bf16(ah[kh], bl, acc[ct], 0, 0, 0);
            }
        }

        // ---- score phase: 4 fenced quarters (proven structure)
#pragma unroll
        for (int q = 0; q < 4; ++q) {
            if (g == q) {
#pragma unroll
                for (int ct = 0; ct < 8; ++ct) {
                    const int col = (ct << 4) + c4;
                    const float b = bEr[ct];
                    f32x4 vq = acc[ct];
                    vq[0] += b; vq[1] += b; vq[2] += b; vq[3] += b;
                    *(f32x4*)(Ebuf_w + col * 4) = vq;   // E^T[col][rr]
                }
            }
            __asm__ volatile("s_waitcnt lgkmcnt(0)" ::: "memory");
            __builtin_amdgcn_sched_barrier(0);
#pragma unroll
            for (int rr = 0; rr < 4; ++rr) {
                const int e = ebaseC + q * 4 + rr;
                const int d = deC[q * 4 + rr];
                const float kq = kv[q * 4 + rr] + qv[q * 4 + rr];
                const float ew = Ebuf_w[h16k * 4 + rr];
                const float eb = Ebuf_w[(h16k + 8) * 4 + rr];
                float sc = kq * ew;
                sc = copysignf(sqrtf(fabsf(sc)), sc) + eb;  // signed sqrt
                wE_out[(size_t)e * 64 + lane] = sc;

                float pp = sc * aw;
                pp += __shfl_xor(pp, 1);
                pp += __shfl_xor(pp, 2);
                pp += __shfl_xor(pp, 4);
                pp = fminf(fmaxf(pp, -CLAMP_V), CLAMP_V);
                const float ex = __expf(pp);
                if (kk == 0) unsafeAtomicAdd(&denom[d * 8 + h], ex);

                float rsum = 0.f;
#pragma unroll
                for (int dd = 0; dd < 8; ++dd) {
                    const float etd = __shfl(sc, (lane & 56) + dd);  // e_t[h,dd]
                    rsum += etd * veR[dd];                           // VeRow[dd,h,kk]
                }
                unsafeAtomicAdd(&wV_num[(size_t)d * 64 + lane],
                                ex * (vv[q * 4 + rr] + rsum));
            }
            __builtin_amdgcn_sched_barrier(0);
        }

        // ---- rotate pipeline state (arN landed during MFMA+score)
#pragma unroll
        for (int p = 0; p < 4; ++p) arC[p] = arN[p];
#pragma unroll
        for (int r = 0; r < 16; ++r) { seC[r] = seN[r]; deC[r] = deN[r]; }
    }
}

// ---------------- Kernel 3: finalize — wV = numer / denom ----------------
__global__ __launch_bounds__(256) void finalize_kernel(
    const float* __restrict__ denom, float* __restrict__ wV)
{
    const int i = blockIdx.x * 256 + threadIdx.x;   // 12500 blocks * 256 = 3.2M
    const int n = i >> 6;
    const int h = (i >> 3) & 7;
    const float dn = denom[n * 8 + h] + 1e-16f;
    wV[i] = wV[i] / dn;
}

extern "C" void kernel_launch(void* const* d_in, const int* in_sizes, int n_in,
                              void* d_out, int out_size, void* d_ws, size_t ws_size,
                              hipStream_t stream) {
    const float* x         = (const float*)d_in[0];
    const float* edge_attr = (const float*)d_in[1];
    const int*   ei        = (const int*)  d_in[2];
    const float* WQ = (const float*)d_in[3];
    const float* bQ = (const float*)d_in[4];
    const float* WK = (const float*)d_in[5];
    const float* bK = (const float*)d_in[6];
    const float* WE = (const float*)d_in[7];
    const float* bE = (const float*)d_in[8];
    const float* WV = (const float*)d_in[9];
    const float* bV = (const float*)d_in[10];
    const float* Aw = (const float*)d_in[11];
    const float* VeRow = (const float*)d_in[12];

    float* out    = (float*)d_out;
    float* wV_out = out;                        // 50000*64 (numerator, then final)
    float* wE_out = out + (size_t)N_NODES * 64; // 800000*64

    float* ws    = (float*)d_ws;
    float* Q     = ws;
    float* K     = ws + 3200000;
    float* V     = ws + 6400000;
    float* denom = ws + 9600000;

    const int* src_idx = ei;
    const int* dst_idx = ei + N_EDGES;

    hipMemsetAsync(wV_out, 0, (size_t)N_NODES * 64 * sizeof(float), stream);
    hipMemsetAsync(denom, 0, (size_t)N_NODES * 8 * sizeof(float), stream);

    qkv_kernel<<<3125, 256, 0, stream>>>(x, WQ, bQ, WK, bK, WV, bV, Q, K, V);
    edge_kernel<<<1024, 256, 0, stream>>>(edge_attr, src_idx, dst_idx, WE, bE, Aw,
                                          Q, K, V, VeRow, wE_out, denom, wV_out);
    finalize_kernel<<<12500, 256, 0, stream>>>(denom, wV_out);
}

// Round 9
// 526.284 us; speedup vs baseline: 1.1551x; 1.1551x over previous
//
#include <hip/hip_runtime.h>
#include <hip/hip_bf16.h>
#include <math.h>

#define N_NODES 50000
#define N_EDGES 800000
#define CLAMP_V 5.0f

typedef short short8 __attribute__((ext_vector_type(8)));
typedef float f32x4  __attribute__((ext_vector_type(4)));

static __device__ inline short f2bf(float x) {
    __hip_bfloat16 h = __float2bfloat16(x);   // RNE
    return __builtin_bit_cast(short, h);
}
static __device__ inline float bf2f(short s) {
    unsigned u = ((unsigned)(unsigned short)s) << 16;
    return __builtin_bit_cast(float, u);
}

// ---------------- Kernel 1: Q/K/V node projections (unchanged, proven) ----------------
__global__ __launch_bounds__(256) void qkv_kernel(
    const float* __restrict__ x,
    const float* __restrict__ WQ, const float* __restrict__ bQ,
    const float* __restrict__ WK, const float* __restrict__ bK,
    const float* __restrict__ WV, const float* __restrict__ bV,
    float* __restrict__ Q, float* __restrict__ K, float* __restrict__ V)
{
    const int t = threadIdx.x;
    const int c = t & 63;
    const int nl = t >> 6;
    const int base = blockIdx.x * 16;

    float accQ[4], accK[4], accV[4];
    int nodes[4];
#pragma unroll
    for (int j = 0; j < 4; ++j) {
        nodes[j] = base + j * 4 + nl;
        accQ[j] = bQ[c]; accK[j] = bK[c]; accV[j] = bV[c];
    }
    for (int k = 0; k < 64; ++k) {
        const float wq = WQ[k * 64 + c];
        const float wk = WK[k * 64 + c];
        const float wv = WV[k * 64 + c];
#pragma unroll
        for (int j = 0; j < 4; ++j) {
            const float xv = x[nodes[j] * 64 + k];
            accQ[j] += xv * wq;
            accK[j] += xv * wk;
            accV[j] += xv * wv;
        }
    }
#pragma unroll
    for (int j = 0; j < 4; ++j) {
        const int n = nodes[j];
        Q[n * 64 + c] = accQ[j];
        K[n * 64 + c] = accK[j];
        V[n * 64 + c] = accV[j];
    }
}

// ---------------- Kernel 2: fused E-GEMM + score + denom + numerator ----------------
// R7 skeleton (proven 263us, VGPR=76, no spill) with ONE change: bE in 8
// per-lane registers (proven correct in R8) -> LDS exactly 40960 B.
// 4 blocks/CU now fit BY LDS (4*40960 = 160 KiB exactly) while VGPR 76 <= 128
// allows 16 waves/CU. launch_bounds stays (256,3): cap 170, no spill
// (R6/R8 lesson: never tighten the VGPR cap below this kernel's live state).
__global__ __launch_bounds__(256, 3) void edge_kernel(
    const float* __restrict__ edge_attr,
    const int* __restrict__ src_idx, const int* __restrict__ dst_idx,
    const float* __restrict__ WE, const float* __restrict__ bE,
    const float* __restrict__ Aw,
    const float* __restrict__ Qn, const float* __restrict__ Kn,
    const float* __restrict__ Vn, const float* __restrict__ VeRow,
    float* __restrict__ wE_out, float* __restrict__ denom,
    float* __restrict__ wV_num)
{
    // [0,16K)=B_hi  [16K,32K)=B_lo  [32K,40K)=E transpose buf (2KB/wave)
    __shared__ __align__(16) char raw[40960];

    short8* Bhi = (short8*)raw;                  // [(ct*2+kh)*64 + lane]
    short8* Blo = (short8*)(raw + 16384);

    const int t = threadIdx.x;
    const int wave = t >> 6;
    const int lane = t & 63;

    // ---- init: bf16 hi/lo B-fragments from global WE
    short* BhiE = (short*)raw;
    short* BloE = (short*)(raw + 16384);
    for (int i = t; i < 8192; i += 256) {
        const int j  = i & 7;
        const int ln = (i >> 3) & 63;
        const int kh = (i >> 9) & 1;
        const int ct = i >> 10;
        const int k   = kh * 32 + ((ln >> 4) << 3) + j;
        const int col = (ct << 4) + (ln & 15);
        const float w = WE[k * 128 + col];
        const short hb = f2bf(w);
        BhiE[i] = hb;
        BloE[i] = f2bf(w - bf2f(hb));
    }
    __syncthreads();

    float* Ebuf_w = (float*)(raw + 32768 + wave * 2048);  // [col*4 + rr]

    const int h    = lane >> 3;
    const int kk   = lane & 7;
    const int g    = lane >> 4;
    const int c4   = lane & 15;
    const int h16k = (h << 4) + kk;

    // loop-invariant weights in registers (global reads, once, L2-hot)
    const float aw = Aw[kk * 8 + h];
    float veR[8];
#pragma unroll
    for (int dd = 0; dd < 8; ++dd) veR[dd] = VeRow[dd * 64 + lane];
    // bias registers: lane's 8 columns (ct<<4)+c4, statically indexed by ct
    float bEr[8];
#pragma unroll
    for (int ct = 0; ct < 8; ++ct) bEr[ct] = bE[(ct << 4) + c4];

    const int G = (int)gridDim.x;

    // ---- pipeline state: current A-raw + indices; next A-raw + indices
    float4 arC[4], arN[4];
    int seC[16], deC[16], seN[16], deN[16];

    // ---- prologue: load A-raw + indices for first iteration
    int it = blockIdx.x;
    {
        const int ebase0 = __builtin_amdgcn_readfirstlane(it * 64 + wave * 16);
#pragma unroll
        for (int p = 0; p < 2; ++p) {
            const float* srcp = edge_attr + (size_t)(ebase0 + c4) * 64 + p * 32 + (g << 3);
            arC[2 * p]     = *(const float4*)srcp;
            arC[2 * p + 1] = *(const float4*)(srcp + 4);
        }
#pragma unroll
        for (int r = 0; r < 16; ++r) {
            seC[r] = src_idx[ebase0 + r];
            deC[r] = dst_idx[ebase0 + r];
        }
    }

    for (; it < 12500; it += G) {
        const int ebaseC = __builtin_amdgcn_readfirstlane(it * 64 + wave * 16);
        const int itN    = it + G;
        const int itNc   = (itN < 12500) ? itN : 0;   // clamped (result unused at tail)
        const int ebaseN = __builtin_amdgcn_readfirstlane(itNc * 64 + wave * 16);

        // ---- convert A(cur) -> bf16 hi/lo (arC landed long ago; no wait)
        short8 ah[2], al[2];
#pragma unroll
        for (int p = 0; p < 2; ++p) {
            const float xv[8] = {arC[2*p].x, arC[2*p].y, arC[2*p].z, arC[2*p].w,
                                 arC[2*p+1].x, arC[2*p+1].y, arC[2*p+1].z, arC[2*p+1].w};
#pragma unroll
            for (int j = 0; j < 8; ++j) {
                const short hb = f2bf(xv[j]);
                ah[p][j] = hb;
                al[p][j] = f2bf(xv[j] - bf2f(hb));
            }
        }

        // ---- next-iteration index scalar loads (lgkm; land during MFMA)
#pragma unroll
        for (int r = 0; r < 16; ++r) {
            seN[r] = src_idx[ebaseN + r];
            deN[r] = dst_idx[ebaseN + r];
        }

        // ---- gathers for CURRENT iteration (consumed in score phase):
        // issue BEFORE arN so score's vmcnt waits don't drain the prefetch
        float vv[16], kv[16], qv[16];
#pragma unroll
        for (int r = 0; r < 16; ++r) vv[r] = Vn[seC[r] * 64 + lane];
#pragma unroll
        for (int r = 0; r < 16; ++r) {
            kv[r] = Kn[seC[r] * 64 + lane];
            qv[r] = Qn[deC[r] * 64 + lane];
        }

        // ---- A(next) raw loads: issued last, consumed at body end
#pragma unroll
        for (int p = 0; p < 2; ++p) {
            const float* srcp = edge_attr + (size_t)(ebaseN + c4) * 64 + p * 32 + (g << 3);
            arN[2 * p]     = *(const float4*)srcp;
            arN[2 * p + 1] = *(const float4*)(srcp + 4);
        }

        // ---- MFMA: acc[ct] = E[16 rows][ct*16..+15]  (3-product bf16 split)
        f32x4 acc[8] = {};
#pragma unroll
        for (int kh = 0; kh < 2; ++kh) {
#pragma unroll
            for (int ct = 0; ct < 8; ++ct) {
                const short8 bh = Bhi[(ct * 2 + kh) * 64 + lane];
                const short8 bl = Blo[(ct * 2 + kh) * 64 + lane];
                acc[ct] = __builtin_amdgcn_mfma_f32_16x16x32_bf16(ah[kh], bh, acc[ct], 0, 0, 0);
                acc[ct] = __builtin_amdgcn_mfma_f32_16x16x32_bf16(al[kh], bh, acc[ct], 0, 0, 0);
                acc[ct] = __builtin_amdgcn_mfma_f32_16x16x32_bf16(ah[kh], bl, acc[ct], 0, 0, 0);
            }
        }

        // ---- score phase: 4 fenced quarters (proven structure)
#pragma unroll
        for (int q = 0; q < 4; ++q) {
            if (g == q) {
#pragma unroll
                for (int ct = 0; ct < 8; ++ct) {
                    const int col = (ct << 4) + c4;
                    const float b = bEr[ct];
                    f32x4 vq = acc[ct];
                    vq[0] += b; vq[1] += b; vq[2] += b; vq[3] += b;
                    *(f32x4*)(Ebuf_w + col * 4) = vq;   // E^T[col][rr]
                }
            }
            __asm__ volatile("s_waitcnt lgkmcnt(0)" ::: "memory");
            __builtin_amdgcn_sched_barrier(0);
#pragma unroll
            for (int rr = 0; rr < 4; ++rr) {
                const int e = ebaseC + q * 4 + rr;
                const int d = deC[q * 4 + rr];
                const float kq = kv[q * 4 + rr] + qv[q * 4 + rr];
                const float ew = Ebuf_w[h16k * 4 + rr];
                const float eb = Ebuf_w[(h16k + 8) * 4 + rr];
                float sc = kq * ew;
                sc = copysignf(sqrtf(fabsf(sc)), sc) + eb;  // signed sqrt
                wE_out[(size_t)e * 64 + lane] = sc;

                float pp = sc * aw;
                pp += __shfl_xor(pp, 1);
                pp += __shfl_xor(pp, 2);
                pp += __shfl_xor(pp, 4);
                pp = fminf(fmaxf(pp, -CLAMP_V), CLAMP_V);
                const float ex = __expf(pp);
                if (kk == 0) unsafeAtomicAdd(&denom[d * 8 + h], ex);

                float rsum = 0.f;
#pragma unroll
                for (int dd = 0; dd < 8; ++dd) {
                    const float etd = __shfl(sc, (lane & 56) + dd);  // e_t[h,dd]
                    rsum += etd * veR[dd];                           // VeRow[dd,h,kk]
                }
                unsafeAtomicAdd(&wV_num[(size_t)d * 64 + lane],
                                ex * (vv[q * 4 + rr] + rsum));
            }
            __builtin_amdgcn_sched_barrier(0);
        }

        // ---- rotate pipeline state (arN landed during MFMA+score)
#pragma unroll
        for (int p = 0; p < 4; ++p) arC[p] = arN[p];
#pragma unroll
        for (int r = 0; r < 16; ++r) { seC[r] = seN[r]; deC[r] = deN[r]; }
    }
}

// ---------------- Kernel 3: finalize — wV = numer / denom ----------------
__global__ __launch_bounds__(256) void finalize_kernel(
    const float* __restrict__ denom, float* __restrict__ wV)
{
    const int i = blockIdx.x * 256 + threadIdx.x;   // 12500 blocks * 256 = 3.2M
    const int n = i >> 6;
    const int h = (i >> 3) & 7;
    const float dn = denom[n * 8 + h] + 1e-16f;
    wV[i] = wV[i] / dn;
}

extern "C" void kernel_launch(void* const* d_in, const int* in_sizes, int n_in,
                              void* d_out, int out_size, void* d_ws, size_t ws_size,
                              hipStream_t stream) {
    const float* x         = (const float*)d_in[0];
    const float* edge_attr = (const float*)d_in[1];
    const int*   ei        = (const int*)  d_in[2];
    const float* WQ = (const float*)d_in[3];
    const float* bQ = (const float*)d_in[4];
    const float* WK = (const float*)d_in[5];
    const float* bK = (const float*)d_in[6];
    const float* WE = (const float*)d_in[7];
    const float* bE = (const float*)d_in[8];
    const float* WV = (const float*)d_in[9];
    const float* bV = (const float*)d_in[10];
    const float* Aw = (const float*)d_in[11];
    const float* VeRow = (const float*)d_in[12];

    float* out    = (float*)d_out;
    float* wV_out = out;                        // 50000*64 (numerator, then final)
    float* wE_out = out + (size_t)N_NODES * 64; // 800000*64

    float* ws    = (float*)d_ws;
    float* Q     = ws;
    float* K     = ws + 3200000;
    float* V     = ws + 6400000;
    float* denom = ws + 9600000;

    const int* src_idx = ei;
    const int* dst_idx = ei + N_EDGES;

    hipMemsetAsync(wV_out, 0, (size_t)N_NODES * 64 * sizeof(float), stream);
    hipMemsetAsync(denom, 0, (size_t)N_NODES * 8 * sizeof(float), stream);

    qkv_kernel<<<3125, 256, 0, stream>>>(x, WQ, bQ, WK, bK, WV, bV, Q, K, V);
    edge_kernel<<<1024, 256, 0, stream>>>(edge_attr, src_idx, dst_idx, WE, bE, Aw,
                                          Q, K, V, VeRow, wE_out, denom, wV_out);
    finalize_kernel<<<12500, 256, 0, stream>>>(denom, wV_out);
}

// Round 10
// 322.750 us; speedup vs baseline: 1.8835x; 1.6306x over previous
//
#include <hip/hip_runtime.h>
#include <hip/hip_bf16.h>
#include <math.h>

#define N_NODES 50000
#define N_EDGES 800000
#define CLAMP_V 5.0f

typedef short short8 __attribute__((ext_vector_type(8)));
typedef float f32x4  __attribute__((ext_vector_type(4)));

static __device__ inline short f2bf(float x) {
    __hip_bfloat16 h = __float2bfloat16(x);   // RNE
    return __builtin_bit_cast(short, h);
}
static __device__ inline float bf2f(short s) {
    unsigned u = ((unsigned)(unsigned short)s) << 16;
    return __builtin_bit_cast(float, u);
}

// ---------------- Kernel 1: Q/K/V node projections (unchanged, proven) ----------------
__global__ __launch_bounds__(256) void qkv_kernel(
    const float* __restrict__ x,
    const float* __restrict__ WQ, const float* __restrict__ bQ,
    const float* __restrict__ WK, const float* __restrict__ bK,
    const float* __restrict__ WV, const float* __restrict__ bV,
    float* __restrict__ Q, float* __restrict__ K, float* __restrict__ V)
{
    const int t = threadIdx.x;
    const int c = t & 63;
    const int nl = t >> 6;
    const int base = blockIdx.x * 16;

    float accQ[4], accK[4], accV[4];
    int nodes[4];
#pragma unroll
    for (int j = 0; j < 4; ++j) {
        nodes[j] = base + j * 4 + nl;
        accQ[j] = bQ[c]; accK[j] = bK[c]; accV[j] = bV[c];
    }
    for (int k = 0; k < 64; ++k) {
        const float wq = WQ[k * 64 + c];
        const float wk = WK[k * 64 + c];
        const float wv = WV[k * 64 + c];
#pragma unroll
        for (int j = 0; j < 4; ++j) {
            const float xv = x[nodes[j] * 64 + k];
            accQ[j] += xv * wq;
            accK[j] += xv * wk;
            accV[j] += xv * wv;
        }
    }
#pragma unroll
    for (int j = 0; j < 4; ++j) {
        const int n = nodes[j];
        Q[n * 64 + c] = accQ[j];
        K[n * 64 + c] = accK[j];
        V[n * 64 + c] = accV[j];
    }
}

// ---------------- Kernel 2: fused E-GEMM + score + denom + numerator ----------------
// EXACT R7 skeleton (proven 263us: launch_bounds(256,3), grid 768, bEs in LDS,
// VGPR 76, 3 blocks/CU). Two surgical additions:
//  (a) Ebuf bank-conflict fix: padded layout word = 4*(col + (col>>3)).
//      Old read Ebuf[ (h*16+kk)*4+rr ] was an 8-way bank conflict (all h
//      collide) on the fenced serial path — matches the 9.6M
//      SQ_LDS_BANK_CONFLICT counter. New layout: 2-way (free). Writes stay
//      16B-aligned f32x4. Ebuf 2304 B/wave -> LDS 42496 -> still 3 blocks/CU.
//  (b) s_setprio(1) around the MFMA cluster (waves here are barrier-free and
//      phase-diverse — the regime where setprio pays).
__global__ __launch_bounds__(256, 3) void edge_kernel(
    const float* __restrict__ edge_attr,
    const int* __restrict__ src_idx, const int* __restrict__ dst_idx,
    const float* __restrict__ WE, const float* __restrict__ bE,
    const float* __restrict__ Aw,
    const float* __restrict__ Qn, const float* __restrict__ Kn,
    const float* __restrict__ Vn, const float* __restrict__ VeRow,
    float* __restrict__ wE_out, float* __restrict__ denom,
    float* __restrict__ wV_num)
{
    // [0,16K)=B_hi  [16K,32K)=B_lo  [32K, 32K+4*2304)=E transpose bufs
    __shared__ __align__(16) char raw[41984];
    __shared__ float bEs[128];

    short8* Bhi = (short8*)raw;                  // [(ct*2+kh)*64 + lane]
    short8* Blo = (short8*)(raw + 16384);

    const int t = threadIdx.x;
    const int wave = t >> 6;
    const int lane = t & 63;

    // ---- init: bf16 hi/lo B-fragments from global WE
    short* BhiE = (short*)raw;
    short* BloE = (short*)(raw + 16384);
    for (int i = t; i < 8192; i += 256) {
        const int j  = i & 7;
        const int ln = (i >> 3) & 63;
        const int kh = (i >> 9) & 1;
        const int ct = i >> 10;
        const int k   = kh * 32 + ((ln >> 4) << 3) + j;
        const int col = (ct << 4) + (ln & 15);
        const float w = WE[k * 128 + col];
        const short hb = f2bf(w);
        BhiE[i] = hb;
        BloE[i] = f2bf(w - bf2f(hb));
    }
    if (t < 128) bEs[t] = bE[t];
    __syncthreads();

    float* Ebuf_w = (float*)(raw + 32768 + wave * 2304);  // padded: word=4*(col+(col>>3))+rr

    const int h    = lane >> 3;
    const int kk   = lane & 7;
    const int g    = lane >> 4;
    const int c4   = lane & 15;
    const int h16k = (h << 4) + kk;
    // padded Ebuf read offsets (col1 = h16k, col2 = h16k+8)
    const int ewoff = (h16k + (h16k >> 3)) << 2;
    const int eboff = ((h16k + 8) + ((h16k + 8) >> 3)) << 2;

    // loop-invariant weights in registers (global reads, once, L2-hot)
    const float aw = Aw[kk * 8 + h];
    float veR[8];
#pragma unroll
    for (int dd = 0; dd < 8; ++dd) veR[dd] = VeRow[dd * 64 + lane];

    const int G = (int)gridDim.x;

    // ---- pipeline state: current A-raw + indices; next A-raw + indices
    float4 arC[4], arN[4];
    int seC[16], deC[16], seN[16], deN[16];

    // ---- prologue: load A-raw + indices for first iteration
    int it = blockIdx.x;
    {
        const int ebase0 = __builtin_amdgcn_readfirstlane(it * 64 + wave * 16);
#pragma unroll
        for (int p = 0; p < 2; ++p) {
            const float* srcp = edge_attr + (size_t)(ebase0 + c4) * 64 + p * 32 + (g << 3);
            arC[2 * p]     = *(const float4*)srcp;
            arC[2 * p + 1] = *(const float4*)(srcp + 4);
        }
#pragma unroll
        for (int r = 0; r < 16; ++r) {
            seC[r] = src_idx[ebase0 + r];
            deC[r] = dst_idx[ebase0 + r];
        }
    }

    for (; it < 12500; it += G) {
        const int ebaseC = __builtin_amdgcn_readfirstlane(it * 64 + wave * 16);
        const int itN    = it + G;
        const int itNc   = (itN < 12500) ? itN : 0;   // clamped (result unused at tail)
        const int ebaseN = __builtin_amdgcn_readfirstlane(itNc * 64 + wave * 16);

        // ---- convert A(cur) -> bf16 hi/lo (arC landed long ago; no wait)
        short8 ah[2], al[2];
#pragma unroll
        for (int p = 0; p < 2; ++p) {
            const float xv[8] = {arC[2*p].x, arC[2*p].y, arC[2*p].z, arC[2*p].w,
                                 arC[2*p+1].x, arC[2*p+1].y, arC[2*p+1].z, arC[2*p+1].w};
#pragma unroll
            for (int j = 0; j < 8; ++j) {
                const short hb = f2bf(xv[j]);
                ah[p][j] = hb;
                al[p][j] = f2bf(xv[j] - bf2f(hb));
            }
        }

        // ---- next-iteration index scalar loads (lgkm; land during MFMA)
#pragma unroll
        for (int r = 0; r < 16; ++r) {
            seN[r] = src_idx[ebaseN + r];
            deN[r] = dst_idx[ebaseN + r];
        }

        // ---- gathers for CURRENT iteration (consumed in score phase):
        // issue BEFORE arN so score's vmcnt waits don't drain the prefetch
        float vv[16], kv[16], qv[16];
#pragma unroll
        for (int r = 0; r < 16; ++r) vv[r] = Vn[seC[r] * 64 + lane];
#pragma unroll
        for (int r = 0; r < 16; ++r) {
            kv[r] = Kn[seC[r] * 64 + lane];
            qv[r] = Qn[deC[r] * 64 + lane];
        }

        // ---- A(next) raw loads: issued last, consumed at body end
#pragma unroll
        for (int p = 0; p < 2; ++p) {
            const float* srcp = edge_attr + (size_t)(ebaseN + c4) * 64 + p * 32 + (g << 3);
            arN[2 * p]     = *(const float4*)srcp;
            arN[2 * p + 1] = *(const float4*)(srcp + 4);
        }

        // ---- MFMA: acc[ct] = E[16 rows][ct*16..+15]  (3-product bf16 split)
        f32x4 acc[8] = {};
        __builtin_amdgcn_s_setprio(1);
#pragma unroll
        for (int kh = 0; kh < 2; ++kh) {
#pragma unroll
            for (int ct = 0; ct < 8; ++ct) {
                const short8 bh = Bhi[(ct * 2 + kh) * 64 + lane];
                const short8 bl = Blo[(ct * 2 + kh) * 64 + lane];
                acc[ct] = __builtin_amdgcn_mfma_f32_16x16x32_bf16(ah[kh], bh, acc[ct], 0, 0, 0);
                acc[ct] = __builtin_amdgcn_mfma_f32_16x16x32_bf16(al[kh], bh, acc[ct], 0, 0, 0);
                acc[ct] = __builtin_amdgcn_mfma_f32_16x16x32_bf16(ah[kh], bl, acc[ct], 0, 0, 0);
            }
        }
        __builtin_amdgcn_s_setprio(0);

        // ---- score phase: 4 fenced quarters (proven structure)
#pragma unroll
        for (int q = 0; q < 4; ++q) {
            if (g == q) {
#pragma unroll
                for (int ct = 0; ct < 8; ++ct) {
                    const int col = (ct << 4) + c4;
                    const float b = bEs[col];
                    f32x4 vq = acc[ct];
                    vq[0] += b; vq[1] += b; vq[2] += b; vq[3] += b;
                    *(f32x4*)(Ebuf_w + ((col + (col >> 3)) << 2)) = vq;   // padded E^T
                }
            }
            __asm__ volatile("s_waitcnt lgkmcnt(0)" ::: "memory");
            __builtin_amdgcn_sched_barrier(0);
#pragma unroll
            for (int rr = 0; rr < 4; ++rr) {
                const int e = ebaseC + q * 4 + rr;
                const int d = deC[q * 4 + rr];
                const float kq = kv[q * 4 + rr] + qv[q * 4 + rr];
                const float ew = Ebuf_w[ewoff + rr];
                const float eb = Ebuf_w[eboff + rr];
                float sc = kq * ew;
                sc = copysignf(sqrtf(fabsf(sc)), sc) + eb;  // signed sqrt
                wE_out[(size_t)e * 64 + lane] = sc;

                float pp = sc * aw;
                pp += __shfl_xor(pp, 1);
                pp += __shfl_xor(pp, 2);
                pp += __shfl_xor(pp, 4);
                pp = fminf(fmaxf(pp, -CLAMP_V), CLAMP_V);
                const float ex = __expf(pp);
                if (kk == 0) unsafeAtomicAdd(&denom[d * 8 + h], ex);

                float rsum = 0.f;
#pragma unroll
                for (int dd = 0; dd < 8; ++dd) {
                    const float etd = __shfl(sc, (lane & 56) + dd);  // e_t[h,dd]
                    rsum += etd * veR[dd];                           // VeRow[dd,h,kk]
                }
                unsafeAtomicAdd(&wV_num[(size_t)d * 64 + lane],
                                ex * (vv[q * 4 + rr] + rsum));
            }
            __builtin_amdgcn_sched_barrier(0);
        }

        // ---- rotate pipeline state (arN landed during MFMA+score)
#pragma unroll
        for (int p = 0; p < 4; ++p) arC[p] = arN[p];
#pragma unroll
        for (int r = 0; r < 16; ++r) { seC[r] = seN[r]; deC[r] = deN[r]; }
    }
}

// ---------------- Kernel 3: finalize — wV = numer / denom ----------------
__global__ __launch_bounds__(256) void finalize_kernel(
    const float* __restrict__ denom, float* __restrict__ wV)
{
    const int i = blockIdx.x * 256 + threadIdx.x;   // 12500 blocks * 256 = 3.2M
    const int n = i >> 6;
    const int h = (i >> 3) & 7;
    const float dn = denom[n * 8 + h] + 1e-16f;
    wV[i] = wV[i] / dn;
}

extern "C" void kernel_launch(void* const* d_in, const int* in_sizes, int n_in,
                              void* d_out, int out_size, void* d_ws, size_t ws_size,
                              hipStream_t stream) {
    const float* x         = (const float*)d_in[0];
    const float* edge_attr = (const float*)d_in[1];
    const int*   ei        = (const int*)  d_in[2];
    const float* WQ = (const float*)d_in[3];
    const float* bQ = (const float*)d_in[4];
    const float* WK = (const float*)d_in[5];
    const float* bK = (const float*)d_in[6];
    const float* WE = (const float*)d_in[7];
    const float* bE = (const float*)d_in[8];
    const float* WV = (const float*)d_in[9];
    const float* bV = (const float*)d_in[10];
    const float* Aw = (const float*)d_in[11];
    const float* VeRow = (const float*)d_in[12];

    float* out    = (float*)d_out;
    float* wV_out = out;                        // 50000*64 (numerator, then final)
    float* wE_out = out + (size_t)N_NODES * 64; // 800000*64

    float* ws    = (float*)d_ws;
    float* Q     = ws;
    float* K     = ws + 3200000;
    float* V     = ws + 6400000;
    float* denom = ws + 9600000;

    const int* src_idx = ei;
    const int* dst_idx = ei + N_EDGES;

    hipMemsetAsync(wV_out, 0, (size_t)N_NODES * 64 * sizeof(float), stream);
    hipMemsetAsync(denom, 0, (size_t)N_NODES * 8 * sizeof(float), stream);

    qkv_kernel<<<3125, 256, 0, stream>>>(x, WQ, bQ, WK, bK, WV, bV, Q, K, V);
    edge_kernel<<<768, 256, 0, stream>>>(edge_attr, src_idx, dst_idx, WE, bE, Aw,
                                         Q, K, V, VeRow, wE_out, denom, wV_out);
    finalize_kernel<<<12500, 256, 0, stream>>>(denom, wV_out);
}